// Round 16
// baseline (255.234 us; speedup 1.0000x reference)
//
#include <hip/hip_runtime.h>

#define N_NODES 25000
#define N_EDGES 400000
#define IN_CH 1024
#define FC 128
#define ADD_CH 20
#define XCH 148   // FC + ADD
#define MID 37
#define OUT_CH 3
#define MAXDEG 64
#define CSTRIDE 16   // cursor padded to one counter per 64B line

typedef short bf16x8 __attribute__((ext_vector_type(8)));
typedef float f32x4 __attribute__((ext_vector_type(4)));
typedef unsigned int u32x4 __attribute__((ext_vector_type(4)));

__device__ __forceinline__ float bflo(unsigned int v) {
    return __builtin_bit_cast(float, v << 16);
}
__device__ __forceinline__ float bfhi(unsigned int v) {
    return __builtin_bit_cast(float, v & 0xffff0000u);
}
// pack 2 f32 -> 2 bf16 (RNE), single VALU op
__device__ __forceinline__ unsigned int cvtpk(float a, float b) {
    unsigned int r;
    asm("v_cvt_pk_bf16_f32 %0, %1, %2" : "=v"(r) : "v"(a), "v"(b));
    return r;
}

// async 16B global->LDS DMA (counts in vmcnt)
__device__ __forceinline__ void gload16(const void* g, void* l) {
    __builtin_amdgcn_global_load_lds(
        (const __attribute__((address_space(1))) unsigned int*)g,
        (__attribute__((address_space(3))) unsigned int*)l,
        16, 0, 0);
}

// ---------------- prep: W swizzle + cursor zero (one dispatch) --------------
#define WSWZ_B 16
#define ZERO_B 49   // 49*512 >= 25000 (each thread zeroes one padded line)

__global__ __launch_bounds__(512) void prep(const float* __restrict__ Wl,
                                            const float* __restrict__ Wr,
                                            ushort* __restrict__ Wpk,
                                            int* __restrict__ cursor) {
    int b = blockIdx.x, t = threadIdx.x;
    if (b < WSWZ_B) {
        int w = t >> 6, lane = t & 63, l15 = lane & 15, q8 = (lane >> 4) * 8;
        int ch = b * 16 + l15;
        const float* src = (ch < FC) ? (Wl + (size_t)ch * IN_CH)
                                     : (Wr + (size_t)(ch - FC) * IN_CH);
        #pragma unroll
        for (int j = 0; j < 4; ++j) {
            int kt = w * 4 + j;
            float4 lo = *(const float4*)(src + kt * 32 + q8);
            float4 hi = *(const float4*)(src + kt * 32 + q8 + 4);
            uint4 pk;
            pk.x = cvtpk(lo.x, lo.y); pk.y = cvtpk(lo.z, lo.w);
            pk.z = cvtpk(hi.x, hi.y); pk.w = cvtpk(hi.z, hi.w);
            ((uint4*)Wpk)[((size_t)kt * 16 + b) * 64 + lane] = pk;
        }
    } else {
        int i = (b - WSWZ_B) * 512 + t;
        if (i < N_NODES) {
            uint4 z = {0, 0, 0, 0};
            uint4* dst = (uint4*)(cursor + (size_t)i * CSTRIDE);
            dst[0] = z; dst[1] = z; dst[2] = z; dst[3] = z;
        }
    }
}

// ---------------- hetero: bf16-A GEMM (depth-3 counted-vmcnt) + ILP build ---
// R15 cycle budget per chunk (4950 cy): LDS-read issue ~2300 (16w x 8 b128),
// A staged as fp32 doubles its LDS traffic, cvtpk x16/wave sits in the
// all-waves compute path. Fix: A converted to bf16 AT STAGE TIME.
//   * waves 0-3 (t<256): A fp32 -> asm-pinned regs (R10 pattern, cannot be
//     compiler-collapsed) -> 4 cvtpk -> 1 ds_write_b128. Unit u=t holds
//     feat[m0+(u>>6)*16+(u&15)][c*32+((u>>4)&3)*8 ..+8] as bf16x8 -- the
//     SAME unit format as W frags, so af is one b128 read at [G*64+lane].
//   * waves 4-7: all W staging via gload16 (4 ops/thread/chunk).
//   Per-chunk LDS: reads 8->6 b128/wave, bank traffic 112->68 KB/block,
//   LDS 72->60 KB. vmcnt per wave-group: A-waves (2), W-waves (8).
//   Same 3-buffer barrier skeleton, same K-order/rounding -> absmax equal.
#define GEMM_B 391    // ceil(25000/64)
#define BUILD_B 196   // ceil(400000/2048)

__global__ __launch_bounds__(512, 4) void gemm_build(const float* __restrict__ A,
                                                     const ushort* __restrict__ Wpk,
                                                     ushort* __restrict__ Py,
                                                     ushort* __restrict__ Pz,
                                                     const int* __restrict__ edges,
                                                     int* __restrict__ cursor,
                                                     int* __restrict__ col) {
    __shared__ uint4 LDS[3][1280];   // [buf][ 0..1023 = W | 1024..1279 = A bf16 ] 60KB
    int b = blockIdx.x, t = threadIdx.x;
    if (b >= GEMM_B) {
        int base = (b - GEMM_B) * 2048 + t;
        int src[4], dst[4], pos[4];
        #pragma unroll
        for (int k = 0; k < 4; ++k) {
            int e = base + k * 512;
            bool v = (e < N_EDGES);
            dst[k] = v ? edges[N_EDGES + e] : 0;
            src[k] = v ? edges[e] : 0;
        }
        #pragma unroll
        for (int k = 0; k < 4; ++k) {
            int e = base + k * 512;
            if (e < N_EDGES)
                pos[k] = atomicAdd(&cursor[(size_t)dst[k] * CSTRIDE], 1);
        }
        #pragma unroll
        for (int k = 0; k < 4; ++k) {
            int e = base + k * 512;
            if (e < N_EDGES && pos[k] < MAXDEG)
                col[dst[k] * MAXDEG + pos[k]] = src[k];
        }
        return;
    }
    int m0 = b * 64;
    int w = t >> 6, lane = t & 63;
    int wm = w >> 2, wn = w & 3;
    int l15 = lane & 15, q = lane >> 4;

    // A staging source (meaningful for t<256 / waves 0-3): unit u = t
    int nodeA = m0 + ((t >> 6) & 3) * 16 + (t & 15);
    if (nodeA >= N_NODES) nodeA = N_NODES - 1;
    unsigned avoff = (unsigned)(((unsigned)nodeA * IN_CH + ((t >> 4) & 3) * 8) * 4);
    const uint4* Wg = (const uint4*)Wpk;

    f32x4 acc[4][2] = {};
    u32x4 aL0, aH0, aL1, aH1;         // A reg banks (waves 0-3)

    #define ISSUE_A(RL, RH, voexpr) { unsigned vo_ = (voexpr);                    \
        asm volatile("global_load_dwordx4 %0, %2, %3\n\t"                         \
                     "global_load_dwordx4 %1, %2, %3 offset:16"                   \
                     : "=&v"(RL), "=&v"(RH) : "v"(vo_), "s"(A) : "memory"); }

    #define WRITE_A(RL, RH, bb) {                                                 \
        f32x4 lo_ = __builtin_bit_cast(f32x4, RL);                                \
        f32x4 hi_ = __builtin_bit_cast(f32x4, RH);                                \
        uint4 pk_;                                                                \
        pk_.x = cvtpk(lo_[0], lo_[1]); pk_.y = cvtpk(lo_[2], lo_[3]);             \
        pk_.z = cvtpk(hi_[0], hi_[1]); pk_.w = cvtpk(hi_[2], hi_[3]);             \
        LDS[bb][1024 + t] = pk_; }

    #define STAGE_W(bb, cidx) {                                                   \
        const uint4* ws_ = Wg + (size_t)(cidx) * 1024 + (w - 4) * 256 + lane;     \
        gload16(ws_ + 0,   &LDS[bb][(w - 4) * 256 + 0]);                          \
        gload16(ws_ + 64,  &LDS[bb][(w - 4) * 256 + 64]);                         \
        gload16(ws_ + 128, &LDS[bb][(w - 4) * 256 + 128]);                        \
        gload16(ws_ + 192, &LDS[bb][(w - 4) * 256 + 192]); }

    #define COMPUTE(bc_)                                                          \
    {                                                                             \
        bf16x8 wf[4];                                                             \
        _Pragma("unroll")                                                         \
        for (int i = 0; i < 4; ++i)                                               \
            wf[i] = *(const bf16x8*)&LDS[bc_][(wn * 4 + i) * 64 + lane];          \
        bf16x8 af[2];                                                             \
        _Pragma("unroll")                                                         \
        for (int g2 = 0; g2 < 2; ++g2)                                            \
            af[g2] = *(const bf16x8*)&LDS[bc_][1024 + (wm * 2 + g2) * 64 + lane]; \
        _Pragma("unroll")                                                         \
        for (int i = 0; i < 4; ++i)                                               \
            _Pragma("unroll")                                                     \
            for (int g2 = 0; g2 < 2; ++g2)                                        \
                acc[i][g2] = __builtin_amdgcn_mfma_f32_16x16x32_bf16(wf[i], af[g2], acc[i][g2], 0, 0, 0); \
    }

    // ---- prologue: chunks 0,1 ----
    if (w < 4) {
        ISSUE_A(aL0, aH0, avoff)
        ISSUE_A(aL1, aH1, avoff + 128u)
        asm volatile("s_waitcnt vmcnt(2)" ::: "memory");   // A(0) landed
        WRITE_A(aL0, aH0, 0)
        asm volatile("s_waitcnt lgkmcnt(0)" ::: "memory");
    } else {
        STAGE_W(0, 0)
        STAGE_W(1, 1)
        asm volatile("s_waitcnt vmcnt(4)" ::: "memory");   // W(0) landed
    }
    __builtin_amdgcn_sched_barrier(0);
    __builtin_amdgcn_s_barrier();
    __builtin_amdgcn_sched_barrier(0);

    #define STEP(c, SL, SH, CL, CH)                                               \
    {                                                                             \
        if (w < 4) {                                                              \
            ISSUE_A(SL, SH, avoff + (unsigned)((c) + 2) * 128u)                   \
            asm volatile("s_waitcnt vmcnt(2)" ::: "memory");                      \
            WRITE_A(CL, CH, bm)                                                   \
            asm volatile("s_waitcnt lgkmcnt(0)" ::: "memory");                    \
        } else {                                                                  \
            STAGE_W(bs, (c) + 2)                                                  \
            asm volatile("s_waitcnt vmcnt(8)" ::: "memory");                      \
        }                                                                         \
        __builtin_amdgcn_sched_barrier(0);                                        \
        __builtin_amdgcn_s_barrier();                                             \
        __builtin_amdgcn_sched_barrier(0);                                        \
        COMPUTE(bc)                                                               \
        __builtin_amdgcn_s_barrier();                                             \
        __builtin_amdgcn_sched_barrier(0);                                        \
        bc = (bc == 2) ? 0 : bc + 1;                                              \
        bm = (bm == 2) ? 0 : bm + 1;                                              \
        bs = (bs == 2) ? 0 : bs + 1;                                              \
    }

    int bc = 0, bm = 1, bs = 2;       // compute / A-write / W-stage buffers
    for (int c = 0; c < 30; c += 2) {
        STEP(c,     aL0, aH0, aL1, aH1)   // even: issue bank0, write bank1
        STEP(c + 1, aL1, aH1, aL0, aH0)   // odd:  issue bank1, write bank0
    }
    // chunk 30: no issue; drain; write A(31) (issued at c=29 -> bank1)
    if (w < 4) {
        asm volatile("s_waitcnt vmcnt(0)" ::: "memory");
        WRITE_A(aL1, aH1, bm)
        asm volatile("s_waitcnt lgkmcnt(0)" ::: "memory");
    } else {
        asm volatile("s_waitcnt vmcnt(0)" ::: "memory");
    }
    __builtin_amdgcn_sched_barrier(0);
    __builtin_amdgcn_s_barrier();
    __builtin_amdgcn_sched_barrier(0);
    COMPUTE(bc)
    __builtin_amdgcn_s_barrier();
    __builtin_amdgcn_sched_barrier(0);
    bc = (bc == 2) ? 0 : bc + 1;
    // chunk 31
    COMPUTE(bc)
    #undef STEP
    #undef COMPUTE
    #undef STAGE_W
    #undef WRITE_A
    #undef ISSUE_A

    // D layout: ch = wn*64 + i*16 + q*4 + reg, node = m0 + wm*32 + g2*16 + l15
    #pragma unroll
    for (int g2 = 0; g2 < 2; ++g2) {
        int node = m0 + wm * 32 + g2 * 16 + l15;
        if (node < N_NODES) {
            ushort* base = (wn < 2) ? (Py + (size_t)node * FC + (wn & 1) * 64 + q * 4)
                                    : (Pz + (size_t)node * FC + (wn & 1) * 64 + q * 4);
            #pragma unroll
            for (int i = 0; i < 4; ++i) {
                f32x4 v = acc[i][g2];
                uint2 pk;
                pk.x = cvtpk(v[0], v[1]);
                pk.y = cvtpk(v[2], v[3]);
                *(uint2*)(base + i * 16) = pk;
            }
        }
    }
}

// ---------------- fused tail v5: gather-first phase order (unchanged) -------
__global__ __launch_bounds__(512) void fused_tail(const ushort* __restrict__ Py,
                                                  const ushort* __restrict__ Pz,
                                                  const int* __restrict__ deg,
                                                  const int* __restrict__ col,
                                                  const float* __restrict__ addf,
                                                  const float* __restrict__ bl,
                                                  const float* __restrict__ W1,
                                                  const float* __restrict__ b1,
                                                  const float* __restrict__ W2,
                                                  const float* __restrict__ b2,
                                                  const float* __restrict__ gamma,
                                                  const float* __restrict__ beta,
                                                  const float* __restrict__ rmean,
                                                  const float* __restrict__ rvar,
                                                  float* __restrict__ out) {
    __shared__ float W1s[XCH][MID + 3];
    __shared__ float xbuf[8][XCH + 4];
    __shared__ float hbuf[8][MID + 3];
    int t = threadIdx.x;
    int w = t >> 6, lane = t & 63;
    int n = blockIdx.x * 8 + w;
    bool valid = (n < N_NODES);

    // ---- phase 1: gather + reduce + x-build (wave-private, no barrier) ----
    int d = valid ? deg[(size_t)n * CSTRIDE] : 0;
    if (d > MAXDEG) d = MAXDEG;
    int g = lane >> 4, c16 = lane & 15;
    float s[8] = {0.f, 0.f, 0.f, 0.f, 0.f, 0.f, 0.f, 0.f};
    if (d > 0) {
        int cidx = col[n * MAXDEG + (lane < d ? lane : 0)];
        for (int i = 0; i < d; i += 16) {
            int e[4];
            uint4 v[4];
            #pragma unroll
            for (int j = 0; j < 4; ++j) {
                int ee = i + g + j * 4;
                e[j] = __shfl(cidx, (ee < d) ? ee : 0);
            }
            #pragma unroll
            for (int j = 0; j < 4; ++j)
                v[j] = *(const uint4*)&Py[(size_t)e[j] * FC + c16 * 8];
            #pragma unroll
            for (int j = 0; j < 4; ++j) {
                if (i + g + j * 4 < d) {
                    s[0] += bflo(v[j].x); s[1] += bfhi(v[j].x);
                    s[2] += bflo(v[j].y); s[3] += bfhi(v[j].y);
                    s[4] += bflo(v[j].z); s[5] += bfhi(v[j].z);
                    s[6] += bflo(v[j].w); s[7] += bfhi(v[j].w);
                }
            }
        }
        #pragma unroll
        for (int r = 0; r < 8; ++r) {
            s[r] += __shfl_xor(s[r], 16);
            s[r] += __shfl_xor(s[r], 32);
        }
    }
    if (valid) {
        if (lane < 16) {
            #pragma unroll
            for (int r = 0; r < 8; ++r) xbuf[w][lane * 8 + r] = s[r];
        }
        float invd = 1.0f / (float)(d > 1 ? d : 1);
        unsigned int vr = *(const unsigned int*)&Pz[(size_t)n * FC + lane * 2];
        float x0 = xbuf[w][2 * lane] * invd + bl[2 * lane] + bflo(vr);
        float x1 = xbuf[w][2 * lane + 1] * invd + bl[2 * lane + 1] + bfhi(vr);
        x0 = (x0 >= 0.f) ? x0 : 0.01f * x0;
        x1 = (x1 >= 0.f) ? x1 : 0.01f * x1;
        xbuf[w][2 * lane] = x0;
        xbuf[w][2 * lane + 1] = x1;
        if (lane < ADD_CH) xbuf[w][FC + lane] = addf[(size_t)n * ADD_CH + lane];
    }

    // ---- phase 2: W1s fill (overlaps other waves' gathers via TLP) ----
    for (int idx = t; idx < MID * XCH; idx += 512) {
        int j = idx / XCH, k = idx - j * XCH;
        W1s[k][j] = W1[idx];
    }
    __syncthreads();

    // ---- phase 3: MLP + store ----
    if (valid) {
        if (lane < MID) {
            float h = b1[lane];
            #pragma unroll 4
            for (int k = 0; k < XCH; ++k) h += W1s[k][lane] * xbuf[w][k];
            h = fmaxf(h, 0.0f);
            h = gamma[lane] * (h - rmean[lane]) * rsqrtf(rvar[lane] + 1e-5f) + beta[lane];
            hbuf[w][lane] = h;
        }
        if (lane < OUT_CH) {
            float o = b2[lane];
            #pragma unroll
            for (int j = 0; j < MID; ++j) o += W2[lane * MID + j] * hbuf[w][j];
            out[(size_t)n * OUT_CH + lane] = o;
        }
    }
}

// ---------------- launch ----------------

extern "C" void kernel_launch(void* const* d_in, const int* in_sizes, int n_in,
                              void* d_out, int out_size, void* d_ws, size_t ws_size,
                              hipStream_t stream) {
    const float* features = (const float*)d_in[0];
    const int*   edges    = (const int*)d_in[1];
    const float* addf     = (const float*)d_in[4];
    const float* Wl       = (const float*)d_in[5];
    const float* bl       = (const float*)d_in[6];
    const float* Wr       = (const float*)d_in[7];
    const float* W1       = (const float*)d_in[8];
    const float* b1       = (const float*)d_in[9];
    const float* W2       = (const float*)d_in[10];
    const float* b2       = (const float*)d_in[11];
    const float* gamma    = (const float*)d_in[12];
    const float* beta     = (const float*)d_in[13];
    const float* rmean    = (const float*)d_in[14];
    const float* rvar     = (const float*)d_in[15];
    float* out = (float*)d_out;

    char* ws = (char*)d_ws;
    size_t off = 0;
    ushort* Py = (ushort*)(ws + off);     off += (size_t)N_NODES * FC * 2;            // 6.4 MB
    ushort* Pz = (ushort*)(ws + off);     off += (size_t)N_NODES * FC * 2;            // 6.4 MB
    ushort* Wpk = (ushort*)(ws + off);    off += (size_t)32 * 16 * 64 * 16;           // 512 KB
    int* cursor = (int*)(ws + off);       off += (size_t)N_NODES * CSTRIDE * 4;       // 1.6 MB
    int* col = (int*)(ws + off);          off += (size_t)N_NODES * MAXDEG * 4;        // 6.4 MB

    prep<<<WSWZ_B + ZERO_B, 512, 0, stream>>>(Wl, Wr, Wpk, cursor);

    gemm_build<<<GEMM_B + BUILD_B, 512, 0, stream>>>(features, Wpk, Py, Pz,
                                                     edges, cursor, col);

    fused_tail<<<(N_NODES + 7) / 8, 512, 0, stream>>>(Py, Pz, cursor, col, addf, bl,
                                                      W1, b1, W2, b2, gamma, beta,
                                                      rmean, rvar, out);
}